// Round 1
// 161.961 us; speedup vs baseline: 1.0498x; 1.0498x over previous
//
#include <hip/hip_runtime.h>
#include <hip/hip_bf16.h>

#define BATCH 32
#define DZ    8192
#define LG    576
#define LL    256
#define CH    512

// ---- ws layout (byte offsets) ----
#define OFF_S      0                          // float[2*1024] raw Gram S
#define OFF_BSUM   8192                       // double[32*5] per-block stats
#define OFF_SELSUM 9472                       // double[4*32] per-(v,b) mse sums
#define OFF_NG     10496                      // float[BATCH*LG]
#define OFF_NL     84224                      // float[BATCH*LL]
#define OFF_ROWNN  116992                     // u64[BATCH*LG]
#define OFF_COLNN  264448                     // u64[BATCH*LL]   (contiguous w/ ROWNN)
#define OFF_ABF    329984                     // bf16 bits [BATCH*LG*CH]
#define OFF_BBF    19204352                   // bf16 bits [BATCH*LL*CH]
#define WS_NEED    27592960

typedef __attribute__((ext_vector_type(8))) short bf16x8;
typedef __attribute__((ext_vector_type(4))) float f32x4;

__device__ __forceinline__ unsigned short f2bf(float x) {
  union { __hip_bfloat16 h; unsigned short u; } cv;
  cv.h = __float2bfloat16(x);
  return cv.u;
}

// -------- fused front kernel --------
// blk [0,32)        : per-feature stats -> bsum
// blk [32,1088)     : raw Gram S entries
// blk [1088,7744)   : prep (fp32->bf16 + row norms + NN init)   [mfma path only]
__global__ __launch_bounds__(256) void k_front(
    const float* __restrict__ za, const float* __restrict__ zb,
    double* __restrict__ bsum, float* __restrict__ S,
    const float* __restrict__ zgf, const float* __restrict__ zlf,
    unsigned short* __restrict__ Abf, unsigned short* __restrict__ Bbf,
    float* __restrict__ ng, float* __restrict__ nl,
    unsigned long long* __restrict__ nnInit) {
  __shared__ float sred[4][5];
  int tid = threadIdx.x, lane = tid & 63, wv = tid >> 6;
  int blk = blockIdx.x;
  if (blk >= 1088) {
    // ---- prep: 4 rows per block, one wave per row ----
    int row = (blk - 1088) * 4 + wv;
    if (lane == 0) nnInit[row] = ~0ull;       // rowNN/colNN contiguous, 1:1 rows
    const float* src; unsigned short* dst; float* nrm;
    if (row < BATCH * LG) {
      src = zgf + (size_t)row * CH; dst = Abf + (size_t)row * CH; nrm = ng + row;
    } else {
      int rr = row - BATCH * LG;
      src = zlf + (size_t)rr * CH; dst = Bbf + (size_t)rr * CH; nrm = nl + rr;
    }
    const float4* s4 = (const float4*)src;
    float4 v0 = s4[lane * 2], v1 = s4[lane * 2 + 1];
    float ss = v0.x * v0.x + v0.y * v0.y + v0.z * v0.z + v0.w * v0.w +
               v1.x * v1.x + v1.y * v1.y + v1.z * v1.z + v1.w * v1.w;
    union { unsigned short h[8]; uint4 u; } pk;
    pk.h[0] = f2bf(v0.x); pk.h[1] = f2bf(v0.y); pk.h[2] = f2bf(v0.z); pk.h[3] = f2bf(v0.w);
    pk.h[4] = f2bf(v1.x); pk.h[5] = f2bf(v1.y); pk.h[6] = f2bf(v1.z); pk.h[7] = f2bf(v1.w);
    *(uint4*)(dst + lane * 8) = pk.u;
    for (int off = 32; off; off >>= 1) ss += __shfl_down(ss, off);
    if (lane == 0) *nrm = ss;
    return;
  }
  if (blk < 32) {
    int i = blk * 256 + tid;                  // feature 0..8191
    float sa = 0.f, qa = 0.f, sb = 0.f, qb = 0.f, si = 0.f;
    #pragma unroll 8
    for (int b = 0; b < BATCH; ++b) {
      float va = za[(size_t)b * DZ + i];
      float vb = zb[(size_t)b * DZ + i];
      sa += va; qa += va * va;
      sb += vb; qb += vb * vb;
      float d = va - vb; si += d * d;
    }
    float ssa = qa - sa * sa * (1.f / 32.f);  // centered SS = 31*var
    float ssb = qb - sb * sb * (1.f / 32.f);
    float v0 = si;
    float v1 = fmaxf(0.f, 1.f - sqrtf(ssa * (1.f / 31.f) + 1e-4f));
    float v2 = fmaxf(0.f, 1.f - sqrtf(ssb * (1.f / 31.f) + 1e-4f));
    float v3 = ssa * ssa, v4 = ssb * ssb;
    for (int off = 32; off; off >>= 1) {
      v0 += __shfl_down(v0, off); v1 += __shfl_down(v1, off);
      v2 += __shfl_down(v2, off); v3 += __shfl_down(v3, off);
      v4 += __shfl_down(v4, off);
    }
    if (lane == 0) {
      sred[wv][0] = v0; sred[wv][1] = v1; sred[wv][2] = v2;
      sred[wv][3] = v3; sred[wv][4] = v4;
    }
    __syncthreads();
    if (tid < 5)
      bsum[blk * 5 + tid] =
          (double)(sred[0][tid] + sred[1][tid] + sred[2][tid] + sred[3][tid]);
  } else {
    int e = blk - 32;                         // 0..1055
    int zi = e >= 528; if (zi) e -= 528;
    const float* z = zi ? zb : za;
    float* Sz = S + zi * 1024;
    int p = 0, rem = e;
    while (rem >= 32 - p) { rem -= 32 - p; ++p; }
    int q = p + rem;
    const float4* zp = (const float4*)(z + (size_t)p * DZ);
    const float4* zq = (const float4*)(z + (size_t)q * DZ);
    float s = 0.f;
    #pragma unroll
    for (int ii = 0; ii < 8; ++ii) {
      int i = tid + ii * 256;
      float4 a = zp[i], b = zq[i];
      s += a.x * b.x + a.y * b.y + a.z * b.z + a.w * b.w;
    }
    for (int off = 32; off; off >>= 1) s += __shfl_down(s, off);
    if (lane == 0) sred[wv][0] = s;
    __syncthreads();
    if (tid == 0) {
      float r = sred[0][0] + sred[1][0] + sred[2][0] + sred[3][0];
      Sz[p * 32 + q] = r;
      if (p != q) Sz[q * 32 + p] = r;
    }
  }
}

// -------- feature-space cdist via bf16 MFMA + fused NN argmin --------
// 64x128 tile, 4 waves in 2x2, wave-tile 32x64, acc[2][4]
__global__ __launch_bounds__(256) void k_feat_mfma(
    const unsigned short* __restrict__ Abf, const unsigned short* __restrict__ Bbf,
    const float* __restrict__ ng, const float* __restrict__ nl,
    unsigned long long* __restrict__ rowNN, unsigned long long* __restrict__ colNN) {
  const int b = blockIdx.z;
  const int row0 = blockIdx.x * 64;           // 9
  const int col0 = blockIdx.y * 128;          // 2
  const int tid = threadIdx.x;
  const int wave = tid >> 6, lane = tid & 63;
  const int m16 = lane & 15, quad = lane >> 4;
  const int wm = wave >> 1, wn = wave & 1;    // row-half (32 rows), col-half (64 cols)

  __shared__ unsigned short As[64][72];
  __shared__ unsigned short Bs[128][72];

  const unsigned short* Ag = Abf + ((size_t)(b * LG + row0)) * CH;
  const unsigned short* Bg = Bbf + ((size_t)(b * LL + col0)) * CH;

  const int sr = tid >> 2, sq = tid & 3;      // A: 64 rows x 32B chunks
  const int br = tid >> 1, bq = tid & 1;      // B: 128 rows x (2x16B + 2x16B) chunks

  f32x4 acc[2][4] = {};

  for (int k0 = 0; k0 < CH; k0 += 64) {
    uint4 a0 = *(const uint4*)(Ag + (size_t)sr * CH + k0 + sq * 16);
    uint4 a1 = *(const uint4*)(Ag + (size_t)sr * CH + k0 + sq * 16 + 8);
    uint4 b0 = *(const uint4*)(Bg + (size_t)br * CH + k0 + bq * 16);
    uint4 b1 = *(const uint4*)(Bg + (size_t)br * CH + k0 + bq * 16 + 8);
    uint4 b2 = *(const uint4*)(Bg + (size_t)br * CH + k0 + bq * 16 + 32);
    uint4 b3 = *(const uint4*)(Bg + (size_t)br * CH + k0 + bq * 16 + 40);
    __syncthreads();
    *(uint4*)&As[sr][sq * 16] = a0; *(uint4*)&As[sr][sq * 16 + 8] = a1;
    *(uint4*)&Bs[br][bq * 16] = b0; *(uint4*)&Bs[br][bq * 16 + 8] = b1;
    *(uint4*)&Bs[br][bq * 16 + 32] = b2; *(uint4*)&Bs[br][bq * 16 + 40] = b3;
    __syncthreads();
    #pragma unroll
    for (int kk = 0; kk < 64; kk += 32) {
      bf16x8 af0 = *(const bf16x8*)&As[wm * 32 + m16][kk + quad * 8];
      bf16x8 af1 = *(const bf16x8*)&As[wm * 32 + 16 + m16][kk + quad * 8];
      bf16x8 bfv[4];
      #pragma unroll
      for (int j = 0; j < 4; ++j)
        bfv[j] = *(const bf16x8*)&Bs[wn * 64 + j * 16 + m16][kk + quad * 8];
      #pragma unroll
      for (int j = 0; j < 4; ++j) {
        acc[0][j] = __builtin_amdgcn_mfma_f32_16x16x32_bf16(af0, bfv[j], acc[0][j], 0, 0, 0);
        acc[1][j] = __builtin_amdgcn_mfma_f32_16x16x32_bf16(af1, bfv[j], acc[1][j], 0, 0, 0);
      }
    }
  }

  float na[2][4], nb[4];
  #pragma unroll
  for (int i = 0; i < 2; ++i)
    #pragma unroll
    for (int r = 0; r < 4; ++r)
      na[i][r] = ng[b * LG + row0 + wm * 32 + i * 16 + quad * 4 + r];
  #pragma unroll
  for (int j = 0; j < 4; ++j)
    nb[j] = nl[b * LL + col0 + wn * 64 + j * 16 + m16];

  // rowNN: min over 4 col-frags then across the 16 m16 lanes
  #pragma unroll
  for (int i = 0; i < 2; ++i) {
    #pragma unroll
    for (int r = 0; r < 4; ++r) {
      unsigned long long p = ~0ull;
      #pragma unroll
      for (int j = 0; j < 4; ++j) {
        float d = fmaxf(na[i][r] + nb[j] - 2.f * acc[i][j][r], 0.f);
        unsigned c = (unsigned)(col0 + wn * 64 + j * 16 + m16);
        unsigned long long pj = (((unsigned long long)__float_as_uint(d)) << 32) | c;
        p = pj < p ? pj : p;
      }
      #pragma unroll
      for (int s = 1; s < 16; s <<= 1) {
        unsigned long long q = __shfl_xor(p, s);
        p = q < p ? q : p;
      }
      if (m16 == 0)
        atomicMin(&rowNN[(size_t)b * LG + row0 + wm * 32 + i * 16 + quad * 4 + r], p);
    }
  }
  // colNN: min over 8 row-elems then across the 4 quads
  #pragma unroll
  for (int j = 0; j < 4; ++j) {
    unsigned long long p = ~0ull;
    #pragma unroll
    for (int i = 0; i < 2; ++i) {
      #pragma unroll
      for (int r = 0; r < 4; ++r) {
        float d = fmaxf(na[i][r] + nb[j] - 2.f * acc[i][j][r], 0.f);
        unsigned rg = (unsigned)(row0 + wm * 32 + i * 16 + quad * 4 + r);
        unsigned long long pr = (((unsigned long long)__float_as_uint(d)) << 32) | rg;
        p = pr < p ? pr : p;
      }
    }
    unsigned long long q = __shfl_xor(p, 16); p = q < p ? q : p;
    q = __shfl_xor(p, 32); p = q < p ? q : p;
    if (quad == 0)
      atomicMin(&colNN[(size_t)b * LL + col0 + wn * 64 + j * 16 + m16], p);
  }
}

// -------- FALLBACK (small ws): fp32 VALU cdist + NN --------
__global__ __launch_bounds__(64) void k_norms(
    const float* __restrict__ zgf, const float* __restrict__ zlf,
    float* __restrict__ ng, float* __restrict__ nl,
    unsigned long long* __restrict__ nnInit) {
  int r = blockIdx.x;
  if (threadIdx.x == 0) nnInit[r] = ~0ull;
  const float* src; float* dst;
  if (r < BATCH * LG) { src = zgf + (size_t)r * CH; dst = ng + r; }
  else { int rr = r - BATCH * LG; src = zlf + (size_t)rr * CH; dst = nl + rr; }
  float s = 0.f;
  for (int j = threadIdx.x; j < CH; j += 64) { float v = src[j]; s += v * v; }
  for (int off = 32; off > 0; off >>= 1) s += __shfl_down(s, off);
  if (threadIdx.x == 0) *dst = s;
}

__global__ __launch_bounds__(256) void k_feat_nn(
    const float* __restrict__ zgf, const float* __restrict__ zlf,
    const float* __restrict__ ng, const float* __restrict__ nl,
    unsigned long long* __restrict__ rowNN, unsigned long long* __restrict__ colNN) {
  const int b = blockIdx.z;
  const int row0 = blockIdx.x * 64;
  const int col0 = blockIdx.y * 128;
  const int tid = threadIdx.x;
  const int tx = tid & 15, ty = tid >> 4;
  __shared__ float As[64][20];
  __shared__ float Bs[128][20];
  __shared__ float Ds[64][130];
  const float* Ag = zgf + ((size_t)b * LG + row0) * CH;
  const float* Bg = zlf + ((size_t)b * LL + col0) * CH;
  float acc[4][8];
  #pragma unroll
  for (int i = 0; i < 4; ++i)
    #pragma unroll
    for (int j = 0; j < 8; ++j) acc[i][j] = 0.f;
  const int ar = tid >> 2;
  const int ak = (tid & 3) * 4;
  for (int k0 = 0; k0 < CH; k0 += 16) {
    float4 av  = *(const float4*)(Ag + (size_t)ar * CH + k0 + ak);
    float4 bv0 = *(const float4*)(Bg + (size_t)ar * CH + k0 + ak);
    float4 bv1 = *(const float4*)(Bg + (size_t)(ar + 64) * CH + k0 + ak);
    __syncthreads();
    *(float4*)&As[ar][ak] = av;
    *(float4*)&Bs[ar][ak] = bv0;
    *(float4*)&Bs[ar + 64][ak] = bv1;
    __syncthreads();
    #pragma unroll
    for (int k = 0; k < 16; ++k) {
      float a0 = As[ty][k], a1 = As[ty + 16][k], a2 = As[ty + 32][k], a3 = As[ty + 48][k];
      float bv[8];
      #pragma unroll
      for (int j = 0; j < 8; ++j) bv[j] = Bs[tx + 16 * j][k];
      #pragma unroll
      for (int j = 0; j < 8; ++j) {
        acc[0][j] += a0 * bv[j]; acc[1][j] += a1 * bv[j];
        acc[2][j] += a2 * bv[j]; acc[3][j] += a3 * bv[j];
      }
    }
  }
  float ngr[4], nlc[8];
  #pragma unroll
  for (int i = 0; i < 4; ++i) ngr[i] = ng[b * LG + row0 + ty + 16 * i];
  #pragma unroll
  for (int j = 0; j < 8; ++j) nlc[j] = nl[b * LL + col0 + tx + 16 * j];
  #pragma unroll
  for (int i = 0; i < 4; ++i)
    #pragma unroll
    for (int j = 0; j < 8; ++j)
      Ds[ty + 16 * i][tx + 16 * j] = fmaxf(ngr[i] + nlc[j] - 2.f * acc[i][j], 0.f);
  __syncthreads();
  if (tid < 64) {
    unsigned long long best = ~0ull;
    for (int c = 0; c < 128; ++c) {
      unsigned long long p =
          ((unsigned long long)__float_as_uint(Ds[tid][c]) << 32) | (unsigned)(col0 + c);
      best = p < best ? p : best;
    }
    atomicMin(&rowNN[(size_t)b * LG + row0 + tid], best);
  } else if (tid < 192) {
    int c = tid - 64;
    unsigned long long best = ~0ull;
    for (int r = 0; r < 64; ++r) {
      unsigned long long p =
          ((unsigned long long)__float_as_uint(Ds[r][c]) << 32) | (unsigned)(row0 + r);
      best = p < best ? p : best;
    }
    atomicMin(&colNN[(size_t)b * LL + col0 + c], best);
  }
}

// -------- selection: compile-time specialized, explicit 8-wide ILP --------
struct SelSmem {
  unsigned long long keys[LG];
  unsigned int nnm[LG];
  float cxy[2 * LG];
  unsigned int plist[40];
  unsigned int cnt;
  float fred[4];
};

template <int V>
__device__ __forceinline__ void sel_case(
    SelSmem& sm, int b,
    const float* __restrict__ zgf, const float* __restrict__ zlf,
    const float* __restrict__ gg, const float* __restrict__ gl,
    const unsigned long long* __restrict__ rowNN,
    const unsigned long long* __restrict__ colNN,
    double* __restrict__ selsum) {
  constexpr bool GDIR = (V == 0 || V == 2);
  constexpr int L1 = GDIR ? LG : LL;
  constexpr int L2 = GDIR ? LL : LG;
  constexpr int M  = GDIR ? 20 : 4;
  constexpr int NR = (L1 + 255) / 256;
  const float* fin  = GDIR ? zgf + (size_t)b * LG * CH : zlf + (size_t)b * LL * CH;
  const float* fcan = GDIR ? zlf + (size_t)b * LL * CH : zgf + (size_t)b * LG * CH;
  int tid = threadIdx.x, lane = tid & 63, wv = tid >> 6;
  if (tid == 0) sm.cnt = 0;

  if constexpr (V < 2) {
    const unsigned long long* src =
        (V == 0) ? rowNN + (size_t)b * LG : colNN + (size_t)b * LL;
    #pragma unroll
    for (int s = 0; s < NR; ++s) {
      int l = tid + s * 256;
      if (l < L1) {
        unsigned long long p = src[l];
        sm.keys[l] = (p & 0xFFFFFFFF00000000ull) | (unsigned)l;
        sm.nnm[l] = (unsigned)(p & 0xFFFFFFFFu);
      }
    }
  } else {
    const float* gin  = (V == 2) ? gg + (size_t)b * LG * 2 : gl + (size_t)b * LL * 2;
    const float* gcan = (V == 2) ? gl + (size_t)b * LL * 2 : gg + (size_t)b * LG * 2;
    #pragma unroll
    for (int s = 0; s < (2 * L2 + 255) / 256; ++s) {
      int i = tid + s * 256;
      if (i < 2 * L2) sm.cxy[i] = gcan[i];
    }
    __syncthreads();
    float x[NR], y[NR], bd[NR];
    unsigned bi[NR];
    #pragma unroll
    for (int s = 0; s < NR; ++s) {
      int l = tid + s * 256;
      x[s] = (l < L1) ? gin[2 * l] : 0.f;
      y[s] = (l < L1) ? gin[2 * l + 1] : 0.f;
      bd[s] = 3.4e38f; bi[s] = 0;
    }
    const float2* c2 = (const float2*)sm.cxy;
    for (int m2 = 0; m2 < L2; m2 += 8) {
      float2 cc[8];                          // 8 LDS loads in flight
      #pragma unroll
      for (int u = 0; u < 8; ++u) cc[u] = c2[m2 + u];
      #pragma unroll
      for (int u = 0; u < 8; ++u)
        #pragma unroll
        for (int s = 0; s < NR; ++s) {
          float dx = x[s] - cc[u].x, dy = y[s] - cc[u].y;
          float d2 = dx * dx + dy * dy;
          if (d2 < bd[s]) { bd[s] = d2; bi[s] = (unsigned)(m2 + u); }  // first-min
        }
    }
    #pragma unroll
    for (int s = 0; s < NR; ++s) {
      int l = tid + s * 256;
      if (l < L1) {
        sm.keys[l] = ((unsigned long long)__float_as_uint(bd[s]) << 32) | (unsigned)l;
        sm.nnm[l] = bi[s];
      }
    }
  }
  __syncthreads();

  // rank count with 8-wide batched LDS reads
  unsigned long long myk[NR];
  int rk[NR];
  #pragma unroll
  for (int s = 0; s < NR; ++s) {
    int l = tid + s * 256;
    myk[s] = (l < L1) ? sm.keys[l] : ~0ull;
    rk[s] = 0;
  }
  for (int j = 0; j < L1; j += 8) {
    unsigned long long kk[8];
    #pragma unroll
    for (int u = 0; u < 8; ++u) kk[u] = sm.keys[j + u];
    #pragma unroll
    for (int u = 0; u < 8; ++u)
      #pragma unroll
      for (int s = 0; s < NR; ++s) rk[s] += (kk[u] < myk[s]) ? 1 : 0;
  }
  #pragma unroll
  for (int s = 0; s < NR; ++s) {
    int l = tid + s * 256;
    if (l < L1 && rk[s] < M) {
      unsigned slot = atomicAdd(&sm.cnt, 1u);
      sm.plist[2 * slot] = (unsigned)l;
      sm.plist[2 * slot + 1] = sm.nnm[l];
    }
  }
  __syncthreads();

  // MSE: wave-per-pair, fully unrolled float4 gathers
  float part = 0.f;
  #pragma unroll
  for (int rr = 0; rr < M / 4; ++rr) {
    int r = wv + rr * 4;
    const float4* a4 = (const float4*)(fin + (size_t)sm.plist[2 * r] * CH);
    const float4* c4 = (const float4*)(fcan + (size_t)sm.plist[2 * r + 1] * CH);
    float4 xa = a4[lane * 2], xb = a4[lane * 2 + 1];
    float4 ya = c4[lane * 2], yb = c4[lane * 2 + 1];
    float d0 = xa.x - ya.x, d1 = xa.y - ya.y, d2 = xa.z - ya.z, d3 = xa.w - ya.w;
    float d4 = xb.x - yb.x, d5 = xb.y - yb.y, d6 = xb.z - yb.z, d7 = xb.w - yb.w;
    part += d0 * d0 + d1 * d1 + d2 * d2 + d3 * d3 +
            d4 * d4 + d5 * d5 + d6 * d6 + d7 * d7;
  }
  for (int s = 32; s; s >>= 1) part += __shfl_down(part, s);
  if (lane == 0) sm.fred[wv] = part;
  __syncthreads();
  if (tid == 0)
    selsum[V * 32 + b] = (double)(sm.fred[0] + sm.fred[1] + sm.fred[2] + sm.fred[3]);
}

__global__ __launch_bounds__(256) void k_sel(
    const float* __restrict__ zgf, const float* __restrict__ zlf,
    const float* __restrict__ gg, const float* __restrict__ gl,
    const unsigned long long* __restrict__ rowNN,
    const unsigned long long* __restrict__ colNN,
    double* __restrict__ selsum) {
  __shared__ SelSmem sm;
  int b = blockIdx.x;
  switch (blockIdx.y) {
    case 0: sel_case<0>(sm, b, zgf, zlf, gg, gl, rowNN, colNN, selsum); break;
    case 1: sel_case<1>(sm, b, zgf, zlf, gg, gl, rowNN, colNN, selsum); break;
    case 2: sel_case<2>(sm, b, zgf, zlf, gg, gl, rowNN, colNN, selsum); break;
    default: sel_case<3>(sm, b, zgf, zlf, gg, gl, rowNN, colNN, selsum); break;
  }
}

// -------- final combine --------
__global__ __launch_bounds__(64) void k_final(
    const double* __restrict__ bsum, const double* __restrict__ selsum,
    const float* __restrict__ S, float* __restrict__ out) {
  __shared__ float t[2][32];
  __shared__ double sacc[5];
  __shared__ double smf[4];
  int lane = threadIdx.x;
  #pragma unroll
  for (int zi = 0; zi < 2; ++zi) {
    if (lane < 32) {
      float tp = 0.f;
      for (int bb = 0; bb < 32; ++bb) tp += S[zi * 1024 + lane * 32 + bb];
      t[zi][lane] = tp * (1.f / 32.f);
    }
  }
  if (lane < 5) {
    double s = 0.0;
    for (int blk = 0; blk < 32; ++blk) s += bsum[blk * 5 + lane];
    sacc[lane] = s;
  }
  if (lane >= 8 && lane < 12) {
    int v = lane - 8;
    double s = 0.0;
    for (int bb = 0; bb < 32; ++bb) s += selsum[v * 32 + bb];
    smf[v] = s;
  }
  __syncthreads();
  double total[2];
  #pragma unroll
  for (int zi = 0; zi < 2; ++zi) {
    float u = 0.f;
    for (int bb = 0; bb < 32; ++bb) u += t[zi][bb];
    u *= (1.f / 32.f);
    double s = 0.0;
    for (int e = lane; e < 1024; e += 64) {
      int p = e >> 5, q = e & 31;
      float G = S[zi * 1024 + e] - t[zi][p] - t[zi][q] + u;
      s += (double)G * (double)G;
    }
    for (int off = 32; off; off >>= 1) s += __shfl_down(s, off);
    total[zi] = s;
  }
  if (lane == 0) {
    double inv_g = sacc[0] / (32.0 * 8192.0);
    double v = 0.5 * (sacc[1] + sacc[2]) / 8192.0;
    double c = (total[0] - sacc[3] + total[1] - sacc[4]) / (961.0 * 8192.0);
    double gloss = 25.0 * inv_g + 25.0 * v + c;
    double mfg = smf[0] / (32.0 * 20.0 * 512.0);
    double mfl = smf[1] / (32.0 * 4.0 * 512.0);
    double mgg = smf[2] / (32.0 * 20.0 * 512.0);
    double mgl = smf[3] / (32.0 * 4.0 * 512.0);
    double lloss = 25.0 * (0.5 * (mfg + mfl) + 0.5 * (mgg + mgl));
    out[0] = (float)(0.25 * gloss + 0.75 * lloss);
  }
}

extern "C" void kernel_launch(void* const* d_in, const int* in_sizes, int n_in,
                              void* d_out, int out_size, void* d_ws, size_t ws_size,
                              hipStream_t stream) {
  const float* zg  = (const float*)d_in[0];
  const float* zl  = (const float*)d_in[1];
  const float* zgf = (const float*)d_in[2];
  const float* zlf = (const float*)d_in[3];
  const float* gg  = (const float*)d_in[4];
  const float* glo = (const float*)d_in[5];

  char* ws = (char*)d_ws;
  float* S       = (float*)(ws + OFF_S);
  double* bsum   = (double*)(ws + OFF_BSUM);
  double* selsum = (double*)(ws + OFF_SELSUM);
  float* ng = (float*)(ws + OFF_NG);
  float* nl = (float*)(ws + OFF_NL);
  unsigned long long* rowNN = (unsigned long long*)(ws + OFF_ROWNN);
  unsigned long long* colNN = (unsigned long long*)(ws + OFF_COLNN);
  unsigned short* Abf = (unsigned short*)(ws + OFF_ABF);
  unsigned short* Bbf = (unsigned short*)(ws + OFF_BBF);

  if (ws_size >= WS_NEED) {
    // fused: stats (32) + gram (1056) + prep (6656)
    k_front<<<32 + 1056 + (BATCH * (LG + LL)) / 4, 256, 0, stream>>>(
        zg, zl, bsum, S, zgf, zlf, Abf, Bbf, ng, nl, rowNN);
    k_feat_mfma<<<dim3(LG / 64, LL / 128, BATCH), 256, 0, stream>>>(
        Abf, Bbf, ng, nl, rowNN, colNN);
  } else {
    k_front<<<32 + 1056, 256, 0, stream>>>(
        zg, zl, bsum, S, zgf, zlf, Abf, Bbf, ng, nl, rowNN);
    k_norms<<<BATCH * (LG + LL), 64, 0, stream>>>(zgf, zlf, ng, nl, rowNN);
    k_feat_nn<<<dim3(LG / 64, LL / 128, BATCH), 256, 0, stream>>>(zgf, zlf, ng, nl, rowNN, colNN);
  }
  k_sel<<<dim3(BATCH, 4), 256, 0, stream>>>(zgf, zlf, gg, glo, rowNN, colNN, selsum);
  k_final<<<1, 64, 0, stream>>>(bsum, selsum, S, (float*)d_out);
}

// Round 2
// 159.439 us; speedup vs baseline: 1.0665x; 1.0158x over previous
//
#include <hip/hip_runtime.h>
#include <hip/hip_bf16.h>

#define BATCH 32
#define DZ    8192
#define LG    576
#define LL    256
#define CH    512

// ---- ws layout (byte offsets) ----
#define OFF_S      0                          // float[2*1024] raw Gram S
#define OFF_BSUM   8192                       // double[32*5]
#define OFF_SELSUM 9472                       // double[4*32]
#define OFF_DONE   10496                      // u32 done counter (zeroed each iter by k_mega)
#define OFF_RNP    10560                      // u64[BATCH*LG*2]  row-NN partials (2 col-blocks)
#define OFF_CNP    305472                     // u64[BATCH*LL*9]  col-NN partials (9 row-blocks)
#define WS_NEED    895296

typedef __attribute__((ext_vector_type(8))) short bf16x8;
typedef __attribute__((ext_vector_type(4))) float f32x4;

__device__ __forceinline__ unsigned short f2bf(float x) {
  union { __hip_bfloat16 h; unsigned short u; } cv;
  cv.h = __float2bfloat16(x);
  return cv.u;
}

__device__ __forceinline__ uint4 pack8(float4 lo, float4 hi) {
  union { unsigned short h[8]; uint4 u; } pk;
  pk.h[0] = f2bf(lo.x); pk.h[1] = f2bf(lo.y); pk.h[2] = f2bf(lo.z); pk.h[3] = f2bf(lo.w);
  pk.h[4] = f2bf(hi.x); pk.h[5] = f2bf(hi.y); pk.h[6] = f2bf(hi.z); pk.h[7] = f2bf(hi.w);
  return pk.u;
}

__device__ __forceinline__ float dot4(float4 v) {
  return v.x * v.x + v.y * v.y + v.z * v.z + v.w * v.w;
}

// -------- selection smem (shared with k_mega's union buffer) --------
struct SelSmem {
  unsigned long long keys[LG];
  unsigned int nnm[LG];
  float cxy[2 * LG];
  unsigned int plist[40];
  unsigned int cnt;
  float fred[4];
};

// V0: global->local feat NN (partials x2)  V1: local->global feat NN (partials x9)
// V2: grid global->local                   V3: grid local->global
template <int V>
__device__ __forceinline__ void sel_case(
    SelSmem& sm, int b,
    const float* __restrict__ zgf, const float* __restrict__ zlf,
    const float* __restrict__ gg, const float* __restrict__ gl,
    const unsigned long long* __restrict__ rowNNp,
    const unsigned long long* __restrict__ colNNp,
    double* __restrict__ selsum) {
  constexpr bool GDIR = (V == 0 || V == 2);
  constexpr int L1 = GDIR ? LG : LL;
  constexpr int L2 = GDIR ? LL : LG;
  constexpr int M  = GDIR ? 20 : 4;
  constexpr int NR = (L1 + 255) / 256;
  const float* fin  = GDIR ? zgf + (size_t)b * LG * CH : zlf + (size_t)b * LL * CH;
  const float* fcan = GDIR ? zlf + (size_t)b * LL * CH : zgf + (size_t)b * LG * CH;
  int tid = threadIdx.x, lane = tid & 63, wv = tid >> 6;
  if (tid == 0) sm.cnt = 0;

  if constexpr (V < 2) {
    constexpr int P = (V == 0) ? 2 : 9;
    const unsigned long long* src =
        (V == 0) ? rowNNp + (size_t)b * LG * 2 : colNNp + (size_t)b * LL * 9;
    #pragma unroll
    for (int s = 0; s < NR; ++s) {
      int l = tid + s * 256;
      if (l < L1) {
        const unsigned long long* q = src + (size_t)l * P;
        unsigned long long p = q[0];
        #pragma unroll
        for (int u = 1; u < P; ++u) { unsigned long long t2 = q[u]; p = t2 < p ? t2 : p; }
        sm.keys[l] = (p & 0xFFFFFFFF00000000ull) | (unsigned)l;
        sm.nnm[l] = (unsigned)(p & 0xFFFFFFFFu);
      }
    }
  } else {
    const float* gin  = (V == 2) ? gg + (size_t)b * LG * 2 : gl + (size_t)b * LL * 2;
    const float* gcan = (V == 2) ? gl + (size_t)b * LL * 2 : gg + (size_t)b * LG * 2;
    #pragma unroll
    for (int s = 0; s < (2 * L2 + 255) / 256; ++s) {
      int i = tid + s * 256;
      if (i < 2 * L2) sm.cxy[i] = gcan[i];
    }
    __syncthreads();
    float x[NR], y[NR], bd[NR];
    unsigned bi[NR];
    #pragma unroll
    for (int s = 0; s < NR; ++s) {
      int l = tid + s * 256;
      x[s] = (l < L1) ? gin[2 * l] : 0.f;
      y[s] = (l < L1) ? gin[2 * l + 1] : 0.f;
      bd[s] = 3.4e38f; bi[s] = 0;
    }
    const float2* c2 = (const float2*)sm.cxy;
    for (int m2 = 0; m2 < L2; m2 += 8) {
      float2 cc[8];
      #pragma unroll
      for (int u = 0; u < 8; ++u) cc[u] = c2[m2 + u];
      #pragma unroll
      for (int u = 0; u < 8; ++u)
        #pragma unroll
        for (int s = 0; s < NR; ++s) {
          float dx = x[s] - cc[u].x, dy = y[s] - cc[u].y;
          float d2 = dx * dx + dy * dy;
          if (d2 < bd[s]) { bd[s] = d2; bi[s] = (unsigned)(m2 + u); }  // first-min
        }
    }
    #pragma unroll
    for (int s = 0; s < NR; ++s) {
      int l = tid + s * 256;
      if (l < L1) {
        sm.keys[l] = ((unsigned long long)__float_as_uint(bd[s]) << 32) | (unsigned)l;
        sm.nnm[l] = bi[s];
      }
    }
  }
  __syncthreads();

  // rank count with 8-wide batched LDS reads
  unsigned long long myk[NR];
  int rk[NR];
  #pragma unroll
  for (int s = 0; s < NR; ++s) {
    int l = tid + s * 256;
    myk[s] = (l < L1) ? sm.keys[l] : ~0ull;
    rk[s] = 0;
  }
  for (int j = 0; j < L1; j += 8) {
    unsigned long long kk[8];
    #pragma unroll
    for (int u = 0; u < 8; ++u) kk[u] = sm.keys[j + u];
    #pragma unroll
    for (int u = 0; u < 8; ++u)
      #pragma unroll
      for (int s = 0; s < NR; ++s) rk[s] += (kk[u] < myk[s]) ? 1 : 0;
  }
  #pragma unroll
  for (int s = 0; s < NR; ++s) {
    int l = tid + s * 256;
    if (l < L1 && rk[s] < M) {
      unsigned slot = atomicAdd(&sm.cnt, 1u);
      sm.plist[2 * slot] = (unsigned)l;
      sm.plist[2 * slot + 1] = sm.nnm[l];
    }
  }
  __syncthreads();

  // MSE: wave-per-pair, fully unrolled float4 gathers
  float part = 0.f;
  #pragma unroll
  for (int rr = 0; rr < M / 4; ++rr) {
    int r = wv + rr * 4;
    const float4* a4 = (const float4*)(fin + (size_t)sm.plist[2 * r] * CH);
    const float4* c4 = (const float4*)(fcan + (size_t)sm.plist[2 * r + 1] * CH);
    float4 xa = a4[lane * 2], xb = a4[lane * 2 + 1];
    float4 ya = c4[lane * 2], yb = c4[lane * 2 + 1];
    float d0 = xa.x - ya.x, d1 = xa.y - ya.y, d2 = xa.z - ya.z, d3 = xa.w - ya.w;
    float d4 = xb.x - yb.x, d5 = xb.y - yb.y, d6 = xb.z - yb.z, d7 = xb.w - yb.w;
    part += d0 * d0 + d1 * d1 + d2 * d2 + d3 * d3 +
            d4 * d4 + d5 * d5 + d6 * d6 + d7 * d7;
  }
  for (int s = 32; s; s >>= 1) part += __shfl_down(part, s);
  if (lane == 0) sm.fred[wv] = part;
  __syncthreads();
  if (tid == 0)
    selsum[V * 32 + b] = (double)(sm.fred[0] + sm.fred[1] + sm.fred[2] + sm.fred[3]);
}

// ==================== mega kernel ====================
// blk [0,576)     : feat-NN MFMA (on-the-fly fp32->bf16 + in-kernel norms, partial NN stores)
// blk [576,608)   : per-feature stats -> bsum      (blk 576 zeroes doneCnt)
// blk [608,1664)  : raw Gram S entries
// blk [1664,1728) : grid-space sel V2/V3
__global__ __launch_bounds__(256) void k_mega(
    const float* __restrict__ za, const float* __restrict__ zb,
    const float* __restrict__ zgf, const float* __restrict__ zlf,
    const float* __restrict__ gg, const float* __restrict__ gl,
    double* __restrict__ bsum, float* __restrict__ S,
    unsigned long long* __restrict__ rowNNp, unsigned long long* __restrict__ colNNp,
    double* __restrict__ selsum, unsigned int* __restrict__ doneCnt) {
  __shared__ __align__(16) char smem[28416];
  int tid = threadIdx.x, lane = tid & 63, wv = tid >> 6;
  int blk = blockIdx.x;

  if (blk < 576) {
    // ---- feat MFMA ----
    // XCD swizzle (576 % 8 == 0): consecutive same-XCD blocks get contiguous work
    int fs = (blk & 7) * 72 + (blk >> 3);
    int b = fs / 18, rr_ = fs % 18;
    int by = rr_ / 9, bx = rr_ % 9;
    int row0 = bx * 64, col0 = by * 128;

    unsigned short (*As)[72] = (unsigned short(*)[72])smem;               // 9216 B
    unsigned short (*Bs)[72] = (unsigned short(*)[72])(smem + 9216);      // 18432 B
    float* Asn = (float*)(smem + 27648);                                  // 256 B
    float* Bsn = (float*)(smem + 27904);                                  // 512 B

    const int m16 = lane & 15, quad = lane >> 4;
    const int wm = wv >> 1, wn = wv & 1;
    const float* Ag = zgf + ((size_t)(b * LG + row0)) * CH;
    const float* Bg = zlf + ((size_t)(b * LL + col0)) * CH;
    const int sr = tid >> 2, sq = tid & 3;   // A: 64 rows x 16-float chunks
    const int br = tid >> 1, bq = tid & 1;   // B: 128 rows x 2x16-float chunks

    f32x4 acc[2][4] = {};
    float ssA = 0.f, ssB = 0.f;

    for (int k0 = 0; k0 < CH; k0 += 64) {
      const float* ap = Ag + (size_t)sr * CH + k0 + sq * 16;
      float4 a0 = *(const float4*)(ap);
      float4 a1 = *(const float4*)(ap + 4);
      float4 a2 = *(const float4*)(ap + 8);
      float4 a3 = *(const float4*)(ap + 12);
      const float* bp = Bg + (size_t)br * CH + k0 + bq * 16;
      float4 b0 = *(const float4*)(bp);
      float4 b1 = *(const float4*)(bp + 4);
      float4 b2 = *(const float4*)(bp + 8);
      float4 b3 = *(const float4*)(bp + 12);
      float4 b4 = *(const float4*)(bp + 32);
      float4 b5 = *(const float4*)(bp + 36);
      float4 b6 = *(const float4*)(bp + 40);
      float4 b7 = *(const float4*)(bp + 44);
      ssA += dot4(a0) + dot4(a1) + dot4(a2) + dot4(a3);
      ssB += dot4(b0) + dot4(b1) + dot4(b2) + dot4(b3) +
             dot4(b4) + dot4(b5) + dot4(b6) + dot4(b7);
      __syncthreads();
      *(uint4*)&As[sr][sq * 16]      = pack8(a0, a1);
      *(uint4*)&As[sr][sq * 16 + 8]  = pack8(a2, a3);
      *(uint4*)&Bs[br][bq * 16]      = pack8(b0, b1);
      *(uint4*)&Bs[br][bq * 16 + 8]  = pack8(b2, b3);
      *(uint4*)&Bs[br][bq * 16 + 32] = pack8(b4, b5);
      *(uint4*)&Bs[br][bq * 16 + 40] = pack8(b6, b7);
      __syncthreads();
      #pragma unroll
      for (int kk = 0; kk < 64; kk += 32) {
        bf16x8 af0 = *(const bf16x8*)&As[wm * 32 + m16][kk + quad * 8];
        bf16x8 af1 = *(const bf16x8*)&As[wm * 32 + 16 + m16][kk + quad * 8];
        bf16x8 bfv[4];
        #pragma unroll
        for (int j = 0; j < 4; ++j)
          bfv[j] = *(const bf16x8*)&Bs[wn * 64 + j * 16 + m16][kk + quad * 8];
        #pragma unroll
        for (int j = 0; j < 4; ++j) {
          acc[0][j] = __builtin_amdgcn_mfma_f32_16x16x32_bf16(af0, bfv[j], acc[0][j], 0, 0, 0);
          acc[1][j] = __builtin_amdgcn_mfma_f32_16x16x32_bf16(af1, bfv[j], acc[1][j], 0, 0, 0);
        }
      }
    }

    // in-kernel norms: reduce per-thread partial squares across chunk owners
    ssA += __shfl_xor(ssA, 1); ssA += __shfl_xor(ssA, 2);
    ssB += __shfl_xor(ssB, 1);
    if (sq == 0) Asn[sr] = ssA;
    if (bq == 0) Bsn[br] = ssB;
    __syncthreads();

    float na[2][4], nb[4];
    #pragma unroll
    for (int i = 0; i < 2; ++i)
      #pragma unroll
      for (int r = 0; r < 4; ++r)
        na[i][r] = Asn[wm * 32 + i * 16 + quad * 4 + r];
    #pragma unroll
    for (int j = 0; j < 4; ++j)
      nb[j] = Bsn[wn * 64 + j * 16 + m16];

    // rowNN partial: min over 4 col-frags then across 16 m16 lanes; plain store
    #pragma unroll
    for (int i = 0; i < 2; ++i) {
      #pragma unroll
      for (int r = 0; r < 4; ++r) {
        unsigned long long p = ~0ull;
        #pragma unroll
        for (int j = 0; j < 4; ++j) {
          float d = fmaxf(na[i][r] + nb[j] - 2.f * acc[i][j][r], 0.f);
          unsigned c = (unsigned)(col0 + wn * 64 + j * 16 + m16);
          unsigned long long pj = (((unsigned long long)__float_as_uint(d)) << 32) | c;
          p = pj < p ? pj : p;
        }
        #pragma unroll
        for (int s = 1; s < 16; s <<= 1) {
          unsigned long long q = __shfl_xor(p, s);
          p = q < p ? q : p;
        }
        if (m16 == 0)
          rowNNp[((size_t)b * LG + row0 + wm * 32 + i * 16 + quad * 4 + r) * 2 + by] = p;
      }
    }
    // colNN partial: min over 8 row-elems then across 4 quads; plain store
    #pragma unroll
    for (int j = 0; j < 4; ++j) {
      unsigned long long p = ~0ull;
      #pragma unroll
      for (int i = 0; i < 2; ++i) {
        #pragma unroll
        for (int r = 0; r < 4; ++r) {
          float d = fmaxf(na[i][r] + nb[j] - 2.f * acc[i][j][r], 0.f);
          unsigned rg = (unsigned)(row0 + wm * 32 + i * 16 + quad * 4 + r);
          unsigned long long pr = (((unsigned long long)__float_as_uint(d)) << 32) | rg;
          p = pr < p ? pr : p;
        }
      }
      unsigned long long q = __shfl_xor(p, 16); p = q < p ? q : p;
      q = __shfl_xor(p, 32); p = q < p ? q : p;
      if (quad == 0)
        colNNp[((size_t)b * LL + col0 + wn * 64 + j * 16 + m16) * 9 + bx] = p;
    }
    return;
  }

  if (blk < 608) {
    // ---- per-feature stats ----
    float (*sred)[5] = (float(*)[5])smem;
    int blkS = blk - 576;
    if (blkS == 0 && tid == 0) *doneCnt = 0;   // reset for k_tail each iteration
    int i = blkS * 256 + tid;
    float sa = 0.f, qa = 0.f, sb = 0.f, qb = 0.f, si = 0.f;
    #pragma unroll 8
    for (int b = 0; b < BATCH; ++b) {
      float va = za[(size_t)b * DZ + i];
      float vb = zb[(size_t)b * DZ + i];
      sa += va; qa += va * va;
      sb += vb; qb += vb * vb;
      float d = va - vb; si += d * d;
    }
    float ssa = qa - sa * sa * (1.f / 32.f);
    float ssb = qb - sb * sb * (1.f / 32.f);
    float v0 = si;
    float v1 = fmaxf(0.f, 1.f - sqrtf(ssa * (1.f / 31.f) + 1e-4f));
    float v2 = fmaxf(0.f, 1.f - sqrtf(ssb * (1.f / 31.f) + 1e-4f));
    float v3 = ssa * ssa, v4 = ssb * ssb;
    for (int off = 32; off; off >>= 1) {
      v0 += __shfl_down(v0, off); v1 += __shfl_down(v1, off);
      v2 += __shfl_down(v2, off); v3 += __shfl_down(v3, off);
      v4 += __shfl_down(v4, off);
    }
    if (lane == 0) {
      sred[wv][0] = v0; sred[wv][1] = v1; sred[wv][2] = v2;
      sred[wv][3] = v3; sred[wv][4] = v4;
    }
    __syncthreads();
    if (tid < 5)
      bsum[blkS * 5 + tid] =
          (double)(sred[0][tid] + sred[1][tid] + sred[2][tid] + sred[3][tid]);
    return;
  }

  if (blk < 1664) {
    // ---- raw Gram entries ----
    float (*sred)[5] = (float(*)[5])smem;
    int e = blk - 608;                         // 0..1055
    int zi = e >= 528; if (zi) e -= 528;
    const float* z = zi ? zb : za;
    float* Sz = S + zi * 1024;
    int p = 0, rem = e;
    while (rem >= 32 - p) { rem -= 32 - p; ++p; }
    int q = p + rem;
    const float4* zp = (const float4*)(z + (size_t)p * DZ);
    const float4* zq = (const float4*)(z + (size_t)q * DZ);
    float s = 0.f;
    #pragma unroll
    for (int ii = 0; ii < 8; ++ii) {
      int i = tid + ii * 256;
      float4 a = zp[i], bb = zq[i];
      s += a.x * bb.x + a.y * bb.y + a.z * bb.z + a.w * bb.w;
    }
    for (int off = 32; off; off >>= 1) s += __shfl_down(s, off);
    if (lane == 0) sred[wv][0] = s;
    __syncthreads();
    if (tid == 0) {
      float r = sred[0][0] + sred[1][0] + sred[2][0] + sred[3][0];
      Sz[p * 32 + q] = r;
      if (p != q) Sz[q * 32 + p] = r;
    }
    return;
  }

  // ---- grid-space selection V2/V3 (independent of feat NN) ----
  {
    SelSmem& sm = *reinterpret_cast<SelSmem*>(smem);
    int e = blk - 1664;
    int b2 = e >> 1;
    if (e & 1) sel_case<3>(sm, b2, zgf, zlf, gg, gl, rowNNp, colNNp, selsum);
    else       sel_case<2>(sm, b2, zgf, zlf, gg, gl, rowNNp, colNNp, selsum);
  }
}

// ==================== tail kernel: sel V0/V1 + last-block final ====================
struct TailSmem {
  SelSmem sel;
  float t[2][32];
  double sacc[5];
  double smf[4];
  int isLast;
};

__global__ __launch_bounds__(256) void k_tail(
    const float* __restrict__ zgf, const float* __restrict__ zlf,
    const float* __restrict__ gg, const float* __restrict__ gl,
    const unsigned long long* __restrict__ rowNNp,
    const unsigned long long* __restrict__ colNNp,
    double* __restrict__ selsum, const double* __restrict__ bsum,
    const float* __restrict__ S, unsigned int* __restrict__ doneCnt,
    float* __restrict__ out) {
  __shared__ TailSmem ts;
  int tid = threadIdx.x;
  int b = blockIdx.x >> 1, V = blockIdx.x & 1;
  if (V == 0) sel_case<0>(ts.sel, b, zgf, zlf, gg, gl, rowNNp, colNNp, selsum);
  else        sel_case<1>(ts.sel, b, zgf, zlf, gg, gl, rowNNp, colNNp, selsum);

  if (tid == 0) {
    __threadfence();
    unsigned r = atomicAdd(doneCnt, 1u);
    ts.isLast = (r == 63) ? 1 : 0;
  }
  __syncthreads();
  if (!ts.isLast) return;
  __threadfence();

  // ---- final combine (all 256 threads enter; work in tid<64) ----
  if (tid < 32) {
    #pragma unroll
    for (int zi = 0; zi < 2; ++zi) {
      float tp = 0.f;
      for (int bb = 0; bb < 32; ++bb) tp += S[zi * 1024 + tid * 32 + bb];
      ts.t[zi][tid] = tp * (1.f / 32.f);
    }
  }
  if (tid < 5) {
    double s = 0.0;
    for (int blk = 0; blk < 32; ++blk) s += bsum[blk * 5 + tid];
    ts.sacc[tid] = s;
  }
  if (tid >= 8 && tid < 12) {
    int v = tid - 8;
    double s = 0.0;
    for (int bb = 0; bb < 32; ++bb) s += selsum[v * 32 + bb];
    ts.smf[v] = s;
  }
  __syncthreads();
  if (tid < 64) {
    double total[2];
    #pragma unroll
    for (int zi = 0; zi < 2; ++zi) {
      float u = 0.f;
      for (int bb = 0; bb < 32; ++bb) u += ts.t[zi][bb];
      u *= (1.f / 32.f);
      double s = 0.0;
      for (int e = tid; e < 1024; e += 64) {
        int p = e >> 5, q = e & 31;
        float G = S[zi * 1024 + e] - ts.t[zi][p] - ts.t[zi][q] + u;
        s += (double)G * (double)G;
      }
      for (int off = 32; off; off >>= 1) s += __shfl_down(s, off);
      total[zi] = s;
    }
    if (tid == 0) {
      double inv_g = ts.sacc[0] / (32.0 * 8192.0);
      double v = 0.5 * (ts.sacc[1] + ts.sacc[2]) / 8192.0;
      double c = (total[0] - ts.sacc[3] + total[1] - ts.sacc[4]) / (961.0 * 8192.0);
      double gloss = 25.0 * inv_g + 25.0 * v + c;
      double mfg = ts.smf[0] / (32.0 * 20.0 * 512.0);
      double mfl = ts.smf[1] / (32.0 * 4.0 * 512.0);
      double mgg = ts.smf[2] / (32.0 * 20.0 * 512.0);
      double mgl = ts.smf[3] / (32.0 * 4.0 * 512.0);
      double lloss = 25.0 * (0.5 * (mfg + mfl) + 0.5 * (mgg + mgl));
      out[0] = (float)(0.25 * gloss + 0.75 * lloss);
    }
  }
}

extern "C" void kernel_launch(void* const* d_in, const int* in_sizes, int n_in,
                              void* d_out, int out_size, void* d_ws, size_t ws_size,
                              hipStream_t stream) {
  const float* zg  = (const float*)d_in[0];
  const float* zl  = (const float*)d_in[1];
  const float* zgf = (const float*)d_in[2];
  const float* zlf = (const float*)d_in[3];
  const float* gg  = (const float*)d_in[4];
  const float* glo = (const float*)d_in[5];

  char* ws = (char*)d_ws;
  float* S       = (float*)(ws + OFF_S);
  double* bsum   = (double*)(ws + OFF_BSUM);
  double* selsum = (double*)(ws + OFF_SELSUM);
  unsigned int* doneCnt = (unsigned int*)(ws + OFF_DONE);
  unsigned long long* rowNNp = (unsigned long long*)(ws + OFF_RNP);
  unsigned long long* colNNp = (unsigned long long*)(ws + OFF_CNP);

  k_mega<<<1728, 256, 0, stream>>>(zg, zl, zgf, zlf, gg, glo,
                                   bsum, S, rowNNp, colNNp, selsum, doneCnt);
  k_tail<<<64, 256, 0, stream>>>(zgf, zlf, gg, glo, rowNNp, colNNp,
                                 selsum, bsum, S, doneCnt, (float*)d_out);
}